// Round 6
// baseline (542.876 us; speedup 1.0000x reference)
//
#include <hip/hip_runtime.h>

// LSTM cell, B=8192, IN=H=2048, fp32 in/out.
// Round 6: register-pipelined phases — each phase issues NEXT phase's
// ds_reads into a spare reg set, barrier, then MFMAs the current set.
// LDS pipe services reads(p+1) under MFMA(p). Compiler-emitted counted
// lgkm waits (no manual lgkm asm). vmcnt(6)@ph0 / vmcnt(4)@ph3-start.
// XCD super-tile, LDS XOR swizzle, setprio. Fused LSTM epilogue.
// Pack: X2 bf16 [8192][4096] = [x|h];  W3 bf16 [8192][4096] with row
//   j = (hc>>4)*64 + gate*16 + (hc&15)  -> per-wave n-fragment == gate.

typedef __attribute__((ext_vector_type(8))) short short8;
typedef __attribute__((ext_vector_type(8))) __bf16 bf16x8;
typedef __attribute__((ext_vector_type(4))) float f32x4;

#define GLDS(gp, lp)                                                        \
  __builtin_amdgcn_global_load_lds(                                         \
      (const __attribute__((address_space(1))) void*)(gp),                  \
      (__attribute__((address_space(3))) void*)(lp), 16, 0, 0)

__device__ __forceinline__ unsigned short f2bf(float f) {
  unsigned u = __builtin_bit_cast(unsigned, f);
  u = (u + 0x7FFFu + ((u >> 16) & 1u)) >> 16;  // RNE
  return (unsigned short)u;
}

// ---- pack [x | h] -> X2 bf16 [8192][4096] ----
__global__ void pack_x_kernel(const float* __restrict__ x,
                              const float* __restrict__ h,
                              short* __restrict__ X2) {
  long tid = (long)blockIdx.x * blockDim.x + threadIdx.x;
  long flat = tid * 8;
  int row = (int)(flat >> 12);
  int k = (int)(flat & 4095);
  const float* src = (k < 2048) ? (x + (long)row * 2048 + k)
                                : (h + (long)row * 2048 + (k - 2048));
  float4 a = *(const float4*)src;
  float4 b = *(const float4*)(src + 4);
  short8 o;
  o[0] = (short)f2bf(a.x); o[1] = (short)f2bf(a.y);
  o[2] = (short)f2bf(a.z); o[3] = (short)f2bf(a.w);
  o[4] = (short)f2bf(b.x); o[5] = (short)f2bf(b.y);
  o[6] = (short)f2bf(b.z); o[7] = (short)f2bf(b.w);
  *(short8*)(X2 + flat) = o;
}

// ---- pack weights -> W3 bf16 [8192][4096]; row j: hc=(j>>6)*16+(j&15), g=(j>>4)&3 ----
__global__ void pack_w_kernel(const float* __restrict__ wxf, const float* __restrict__ wxi,
                              const float* __restrict__ wxo, const float* __restrict__ wxc,
                              const float* __restrict__ whf, const float* __restrict__ whi,
                              const float* __restrict__ who, const float* __restrict__ whc,
                              short* __restrict__ W3) {
  long tid = (long)blockIdx.x * blockDim.x + threadIdx.x;
  long flat = tid * 8;
  int j = (int)(flat >> 12);
  int k = (int)(flat & 4095);
  int hc = ((j >> 6) << 4) | (j & 15);
  int g = (j >> 4) & 3;
  const float* base;
  if (k < 2048) {
    const float* wx = (g == 0) ? wxf : (g == 1) ? wxi : (g == 2) ? wxo : wxc;
    base = wx + (long)hc * 2048 + k;
  } else {
    const float* wh = (g == 0) ? whf : (g == 1) ? whi : (g == 2) ? who : whc;
    base = wh + (long)hc * 2048 + (k - 2048);
  }
  float4 a = *(const float4*)base;
  float4 b = *(const float4*)(base + 4);
  short8 o;
  o[0] = (short)f2bf(a.x); o[1] = (short)f2bf(a.y);
  o[2] = (short)f2bf(a.z); o[3] = (short)f2bf(a.w);
  o[4] = (short)f2bf(b.x); o[5] = (short)f2bf(b.y);
  o[6] = (short)f2bf(b.z); o[7] = (short)f2bf(b.w);
  *(short8*)(W3 + flat) = o;
}

// ---- 256x256 fused GEMM + LSTM epilogue ----
// LDS per buffer: q0 A-kh0 @0, q1 B-kh0 @16K, q2 A-kh1 @32K, q3 B-kh1 @48K.
// 16B-chunk swizzle: slot ^= (r>>1)&3 (involution on source + ds_read).
// Pipeline (reads one phase ahead; reg sets aP,aQ,aR,aS / bP,bQ):
//  ph0: rd aQ<-cur q0.mh1 | stage q0,q1,q3(t+1)->nxt | vmcnt(6) BAR | MFMA aP*bP
//  ph1: rd aR<-cur q2.mh0, bQ<-cur q3 | stage q2(t+1)->nxt | BAR | MFMA aQ*bP
//  ph2: rd aS<-cur q2.mh1 | BAR | MFMA aR*bQ
//  ph3: vmcnt(4) BAR | rd aP<-nxt q0.mh0, bP<-nxt q1 | MFMA aS*bQ
__global__ __launch_bounds__(512, 2) void lstm_fused_gemm(
    const short* __restrict__ X2, const short* __restrict__ W3,
    const float* __restrict__ cin,
    const float* __restrict__ bF, const float* __restrict__ bI,
    const float* __restrict__ bO, const float* __restrict__ bC,
    float* __restrict__ hout, float* __restrict__ cout_) {
  __shared__ __align__(16) short lds[65536];  // 128 KiB

  const int tid = threadIdx.x;
  const int lane = tid & 63;
  const int w = tid >> 6;        // 0..7
  const int wm = w >> 2;         // 0..1  (M half, 128 rows)
  const int wn = w & 3;          // 0..3  (N quarter, 64 cols)

  // T1 + within-XCD 2D super-tile: bid = xcd + 8*m4 + 32*bN (bijective).
  const int bid = blockIdx.x;
  const int bM = (bid & 7) * 4 + ((bid >> 3) & 3);  // 0..31
  const int bN = bid >> 5;                          // 0..31

  // --- staging geometry ---
  const int ci = w * 64 + lane;
  const int r0 = ci >> 2;                       // 0..127
  const int ss = (ci & 3) ^ ((r0 >> 1) & 3);    // pre-swizzled source slot
  const short* aRow0 = X2 + ((size_t)(bM * 256 + r0)) * 4096 + ss * 8;
  const short* aRow1 = aRow0 + (size_t)128 * 4096;
  const short* bRow0 = W3 + ((size_t)(bN * 256 + r0)) * 4096 + ss * 8;
  const short* bRow1 = bRow0 + (size_t)128 * 4096;
  const int wOff = w * 1024;

#define STAGE2(q, tt, bb) do {                                               \
    const int _kh = (q) >> 1;                                                \
    const short* _g0; const short* _g1;                                      \
    if ((q) == 0 || (q) == 2) {                                              \
      _g0 = aRow0 + (tt) * 64 + _kh * 32;                                    \
      _g1 = aRow1 + (tt) * 64 + _kh * 32;                                    \
    } else {                                                                 \
      _g0 = bRow0 + (tt) * 64 + _kh * 32;                                    \
      _g1 = bRow1 + (tt) * 64 + _kh * 32;                                    \
    }                                                                        \
    char* _l0 = (char*)lds + (bb) * 65536 + (q) * 16384 + wOff;              \
    GLDS(_g0, _l0);                                                          \
    GLDS(_g1, _l0 + 8192);                                                   \
  } while (0)

  // --- ds_read geometry ---
  const int lr = lane & 15, hi = lane >> 4;
  const int swz = ((hi ^ ((lr >> 1) & 3)) << 4);
  const int aoff = wm * 8192 + lr * 64 + swz;          // + m*1024 (+32768 kh1)
  const int boff = 16384 + wn * 4096 + lr * 64 + swz;  // + n*1024 (+32768 kh1)

#define LDSRD(off) (*(const bf16x8*)((const char*)lds + (off)))
#define MFMA_(a, b, c) __builtin_amdgcn_mfma_f32_16x16x32_bf16((a), (b), (c), 0, 0, 0)

  f32x4 acc[8][4] = {};  // [m][n==gate]
  bf16x8 aP[4], aQ[4], aR[4], aS[4], bP[4], bQ[4];

  // --- prologue: tile0 -> buf0; drain; barrier; read-ahead for ph0(t=0) ---
  STAGE2(0, 0, 0); STAGE2(1, 0, 0); STAGE2(3, 0, 0); STAGE2(2, 0, 0);
  asm volatile("s_waitcnt vmcnt(0)" ::: "memory");
  __builtin_amdgcn_s_barrier();
#pragma unroll
  for (int i = 0; i < 4; ++i) aP[i] = LDSRD(aoff + i * 1024);
#pragma unroll
  for (int n = 0; n < 4; ++n) bP[n] = LDSRD(boff + n * 1024);

#pragma unroll 2
  for (int t = 0; t < 64; ++t) {
    const int cur = t & 1, nxt = cur ^ 1;
    const int bo = cur << 16, bon = nxt << 16;
    const int t1 = (t + 1) & 63;   // t=63 stages dummy (never read; safe)

    // ---- ph0: rd aQ (ph1 operands); stage q0,q1,q3(t+1); MFMA aP*bP ----
#pragma unroll
    for (int i = 0; i < 4; ++i) aQ[i] = LDSRD(bo + aoff + (4 + i) * 1024);
    STAGE2(0, t1, nxt);
    STAGE2(1, t1, nxt);
    STAGE2(3, t1, nxt);
    asm volatile("s_waitcnt vmcnt(6)" ::: "memory");   // q2,q3(t) landed
    __builtin_amdgcn_s_barrier();
    __builtin_amdgcn_s_setprio(1);
#pragma unroll
    for (int n = 0; n < 4; ++n)
#pragma unroll
      for (int i = 0; i < 4; ++i) acc[i][n] = MFMA_(aP[i], bP[n], acc[i][n]);
    __builtin_amdgcn_s_setprio(0);

    // ---- ph1: rd aR,bQ (ph2 operands); stage q2(t+1); MFMA aQ*bP ----
#pragma unroll
    for (int i = 0; i < 4; ++i) aR[i] = LDSRD(bo + aoff + 32768 + i * 1024);
#pragma unroll
    for (int n = 0; n < 4; ++n) bQ[n] = LDSRD(bo + boff + 32768 + n * 1024);
    STAGE2(2, t1, nxt);
    __builtin_amdgcn_s_barrier();
    __builtin_amdgcn_s_setprio(1);
#pragma unroll
    for (int n = 0; n < 4; ++n)
#pragma unroll
      for (int i = 0; i < 4; ++i) acc[4 + i][n] = MFMA_(aQ[i], bP[n], acc[4 + i][n]);
    __builtin_amdgcn_s_setprio(0);

    // ---- ph2: rd aS (ph3 operands); MFMA aR*bQ ----
#pragma unroll
    for (int i = 0; i < 4; ++i) aS[i] = LDSRD(bo + aoff + 32768 + (4 + i) * 1024);
    __builtin_amdgcn_s_barrier();
    __builtin_amdgcn_s_setprio(1);
#pragma unroll
    for (int n = 0; n < 4; ++n)
#pragma unroll
      for (int i = 0; i < 4; ++i) acc[i][n] = MFMA_(aR[i], bQ[n], acc[i][n]);
    __builtin_amdgcn_s_setprio(0);

    // ---- ph3: vmcnt(4); barrier; rd aP,bP <- nxt (ph0(t+1)); MFMA aS*bQ ----
    asm volatile("s_waitcnt vmcnt(4)" ::: "memory");   // q0,q1(t+1) landed
    __builtin_amdgcn_s_barrier();
#pragma unroll
    for (int i = 0; i < 4; ++i) aP[i] = LDSRD(bon + aoff + i * 1024);
#pragma unroll
    for (int n = 0; n < 4; ++n) bP[n] = LDSRD(bon + boff + n * 1024);
    __builtin_amdgcn_s_setprio(1);
#pragma unroll
    for (int n = 0; n < 4; ++n)
#pragma unroll
      for (int i = 0; i < 4; ++i) acc[4 + i][n] = MFMA_(aS[i], bQ[n], acc[4 + i][n]);
    __builtin_amdgcn_s_setprio(0);
  }

  // ---- fused LSTM epilogue: gate g == fragment n; per-lane ----
  const int hc = bN * 64 + wn * 16 + lr;
  const float vbf = bF[hc], vbi = bI[hc], vbo = bO[hc], vbc = bC[hc];
#pragma unroll
  for (int m = 0; m < 8; ++m) {
    const int rbase = bM * 256 + wm * 128 + m * 16 + hi * 4;
#pragma unroll
    for (int v = 0; v < 4; ++v) {
      const size_t idx = (size_t)(rbase + v) * 2048 + hc;
      float gf = acc[m][0][v] + vbf;
      float gi = acc[m][1][v] + vbi;
      float go = acc[m][2][v] + vbo;
      float gc = acc[m][3][v] + vbc;
      float fg = 1.f / (1.f + __expf(-gf));
      float ig = 1.f / (1.f + __expf(-gi));
      float og = 1.f / (1.f + __expf(-go));
      float ct = 2.f / (1.f + __expf(-2.f * gc)) - 1.f;
      float cn = fg * cin[idx] + ig * ct;
      float hn = og * (2.f / (1.f + __expf(-2.f * cn)) - 1.f);
      hout[idx] = hn;
      cout_[idx] = cn;
    }
  }
}

extern "C" void kernel_launch(void* const* d_in, const int* in_sizes, int n_in,
                              void* d_out, int out_size, void* d_ws, size_t ws_size,
                              hipStream_t stream) {
  const float* x    = (const float*)d_in[0];
  const float* h    = (const float*)d_in[1];
  const float* c    = (const float*)d_in[2];
  const float* w_xf = (const float*)d_in[3];
  const float* w_hf = (const float*)d_in[4];
  const float* b_f  = (const float*)d_in[5];
  const float* w_xi = (const float*)d_in[6];
  const float* w_hi = (const float*)d_in[7];
  const float* b_i  = (const float*)d_in[8];
  const float* w_xo = (const float*)d_in[9];
  const float* w_ho = (const float*)d_in[10];
  const float* b_o  = (const float*)d_in[11];
  const float* w_xc = (const float*)d_in[12];
  const float* w_hc = (const float*)d_in[13];
  const float* b_c  = (const float*)d_in[14];

  float* hout  = (float*)d_out;
  float* cout_ = hout + (size_t)8192 * 2048;

  short* X2 = (short*)d_ws;                       // 64 MiB
  short* W3 = X2 + (size_t)8192 * 4096;           // 64 MiB

  const int packBlocks = (int)(((long)8192 * 4096 / 8) / 256);  // 16384
  pack_x_kernel<<<packBlocks, 256, 0, stream>>>(x, h, X2);
  pack_w_kernel<<<packBlocks, 256, 0, stream>>>(w_xf, w_xi, w_xo, w_xc,
                                                w_hf, w_hi, w_ho, w_hc, W3);

  lstm_fused_gemm<<<1024, 512, 0, stream>>>(X2, W3, c, b_f, b_i, b_o, b_c,
                                            hout, cout_);
}